// Round 14
// baseline (311.540 us; speedup 1.0000x reference)
//
// round 14: denominator-deferred attention — m̂ upper bound (precomputed max_en),
//           unnormalized p written single-pass, row-normalization folded into finish_layer
#include <hip/hip_runtime.h>
#include <math.h>

#define NROW 4096
#define ALPHA_SLOPE 0.2f
#define CSRW 320

typedef __attribute__((ext_vector_type(8))) short bf16x8;
typedef __attribute__((ext_vector_type(4))) float f32x4;

__device__ __forceinline__ ushort f2bf(float f) {
    union { float f; unsigned u; } v; v.f = f;
    unsigned r = v.u + 0x7fffu + ((v.u >> 16) & 1u);   // RNE
    return (ushort)(r >> 16);
}
__device__ __forceinline__ float bf2f(ushort u) {
    union { unsigned u; float f; } v; v.u = ((unsigned)u) << 16;
    return v.f;
}

// ================= bf16 MFMA GEMM, BK=64, both-sides-swizzled LDS =================
// Tile (MF*32) x (NF*32), 4 waves (2x2), BK=64, split-K via grid.z.
template<int MF, int NF>
__global__ __launch_bounds__(256)
void gemm_bf16(const ushort* __restrict__ A, const ushort* __restrict__ Bt,
               float* __restrict__ C, float* __restrict__ P,
               int M, int N, int K, int Ks)
{
    constexpr int BM = MF * 32;
    constexpr int BN = NF * 32;
    __shared__ ushort As[BM * 64];
    __shared__ ushort Bs[BN * 64];
    const int tid  = threadIdx.x;
    const int lane = tid & 63;
    const int wave = tid >> 6;
    const int wr = wave >> 1, wc = wave & 1;
    const int row0 = blockIdx.y * BM;
    const int col0 = blockIdx.x * BN;
    const size_t koff = (size_t)blockIdx.z * Ks;

    f32x4 acc[MF][NF];
    #pragma unroll
    for (int i = 0; i < MF; ++i)
        #pragma unroll
        for (int j = 0; j < NF; ++j) acc[i][j] = (f32x4){0.f, 0.f, 0.f, 0.f};

    const ushort* pA[MF]; int dA[MF];
    #pragma unroll
    for (int j = 0; j < MF; ++j) {
        const int s = tid + 256 * j;
        const int r = s >> 3, c = s & 7;
        pA[j] = A + (size_t)(row0 + r) * K + koff + (size_t)(c ^ (r & 7)) * 8;
        dA[j] = s * 8;
    }
    const ushort* pB[NF]; int dB[NF];
    #pragma unroll
    for (int j = 0; j < NF; ++j) {
        const int s = tid + 256 * j;
        const int r = s >> 3, c = s & 7;
        const int rg = (col0 + r < N) ? (col0 + r) : (N - 1);
        pB[j] = Bt + (size_t)rg * K + koff + (size_t)(c ^ (r & 7)) * 8;
        dB[j] = s * 8;
    }

    const int arow0 = wr * (MF * 16) + (lane & 15);
    const int brow0 = wc * (NF * 16) + (lane & 15);
    const int acg   = lane >> 4;

    bf16x8 vA[MF], vB[NF];
    #pragma unroll
    for (int j = 0; j < MF; ++j) vA[j] = *(const bf16x8*)(pA[j]);
    #pragma unroll
    for (int j = 0; j < NF; ++j) vB[j] = *(const bf16x8*)(pB[j]);

    for (int k0 = 0; k0 < Ks; k0 += 64) {
        __syncthreads();
        #pragma unroll
        for (int j = 0; j < MF; ++j) *(bf16x8*)(As + dA[j]) = vA[j];
        #pragma unroll
        for (int j = 0; j < NF; ++j) *(bf16x8*)(Bs + dB[j]) = vB[j];
        __syncthreads();
        if (k0 + 64 < Ks) {
            #pragma unroll
            for (int j = 0; j < MF; ++j) vA[j] = *(const bf16x8*)(pA[j] + k0 + 64);
            #pragma unroll
            for (int j = 0; j < NF; ++j) vB[j] = *(const bf16x8*)(pB[j] + k0 + 64);
        }
        #pragma unroll
        for (int kk = 0; kk < 2; ++kk) {
            const int Q = kk * 4 + acg;
            bf16x8 af[MF], bfr[NF];
            #pragma unroll
            for (int mi = 0; mi < MF; ++mi) {
                const int r = arow0 + mi * 16;
                af[mi] = *(const bf16x8*)(As + (r * 8 + (Q ^ (r & 7))) * 8);
            }
            #pragma unroll
            for (int ni = 0; ni < NF; ++ni) {
                const int r = brow0 + ni * 16;
                bfr[ni] = *(const bf16x8*)(Bs + (r * 8 + (Q ^ (r & 7))) * 8);
            }
            #pragma unroll
            for (int mi = 0; mi < MF; ++mi)
                #pragma unroll
                for (int ni = 0; ni < NF; ++ni)
                    acc[mi][ni] = __builtin_amdgcn_mfma_f32_16x16x32_bf16(
                        af[mi], bfr[ni], acc[mi][ni], 0, 0, 0);
        }
    }

    float* outp = (blockIdx.z == gridDim.z - 1) ? C : (P + (size_t)blockIdx.z * M * N);
    const int crow  = row0 + wr * (MF * 16) + (lane >> 4) * 4;
    const int ccol0 = col0 + wc * (NF * 16) + (lane & 15);
    #pragma unroll
    for (int mi = 0; mi < MF; ++mi)
        #pragma unroll
        for (int ni = 0; ni < NF; ++ni) {
            const int cc = ccol0 + ni * 16;
            if (cc < N) {
                #pragma unroll
                for (int j = 0; j < 4; ++j)
                    outp[(size_t)(crow + mi * 16 + j) * N + cc] = acc[mi][ni][j];
            }
        }
}

// C[i] += sum_{s<nm1} P[s][i]  (fixed order — deterministic)
__global__ void reduce_k(float4* __restrict__ C, const float4* __restrict__ P,
                         int nm1, int n4)
{
    for (int i = blockIdx.x * 256 + threadIdx.x; i < n4; i += gridDim.x * 256) {
        float4 c = C[i];
        for (int s = 0; s < nm1; ++s) {
            const float4 p = P[(size_t)s * n4 + i];
            c.x += p.x; c.y += p.y; c.z += p.z; c.w += p.w;
        }
        C[i] = c;
    }
}

// ===== finish_layer: sum split-K partials, row-scale by linv, ELU, optional mix =====
// shift = log2(D/4); row = i >> shift.
__global__ void finish_layer(const float4* __restrict__ C, const float4* __restrict__ P,
                             int nm1, int n4, const float4* __restrict__ enc,
                             ushort4* __restrict__ outb, float4* __restrict__ outf,
                             const float* __restrict__ linv, int shift)
{
    for (int i = blockIdx.x * 256 + threadIdx.x; i < n4; i += gridDim.x * 256) {
        float4 s = C[i];
        for (int t = 0; t < nm1; ++t) {
            const float4 p = P[(size_t)t * n4 + i];
            s.x += p.x; s.y += p.y; s.z += p.z; s.w += p.w;
        }
        const float li = linv[i >> shift];
        s.x *= li; s.y *= li; s.z *= li; s.w *= li;
        float4 h;
        h.x = (s.x > 0.f) ? s.x : expm1f(s.x);
        h.y = (s.y > 0.f) ? s.y : expm1f(s.y);
        h.z = (s.z > 0.f) ? s.z : expm1f(s.z);
        h.w = (s.w > 0.f) ? s.w : expm1f(s.w);
        if (outf) outf[i] = h;
        if (outb) {
            const float4 e = enc[i];
            ushort4 o;
            o.x = f2bf(0.6f * h.x + 0.4f * e.x);
            o.y = f2bf(0.6f * h.y + 0.4f * e.y);
            o.z = f2bf(0.6f * h.z + 0.4f * e.z);
            o.w = f2bf(0.6f * h.w + 0.4f * e.w);
            outb[i] = o;
        }
    }
}

// ===== max_en: men[0] = max_j en[j] (one block) =====
__global__ __launch_bounds__(256)
void max_en(const float* __restrict__ en, float* __restrict__ men)
{
    const int tid = threadIdx.x, lane = tid & 63, w = tid >> 6;
    float m = -3.0e38f;
    for (int j = tid; j < NROW; j += 256) m = fmaxf(m, en[j]);
    #pragma unroll
    for (int off = 32; off; off >>= 1) m = fmaxf(m, __shfl_xor(m, off));
    __shared__ float sm[4];
    if (lane == 0) sm[w] = m;
    __syncthreads();
    if (tid == 0) men[0] = fmaxf(fmaxf(sm[0], sm[1]), fmaxf(sm[2], sm[3]));
}

// ===== attn_build_l1 (v3): single-pass with m̂ bound; UNNORMALIZED p + linv =====
// Reads f32 adj+M, writes dense bf16 p_unnorm (re-inits attnb each call),
// CSR sidecar, and linv[i] = 1/sum(bf16-rounded p).
__global__ __launch_bounds__(256)
void attn_build_l1(const float4* __restrict__ adj, const float4* __restrict__ Mm,
                   const float* __restrict__ es, const float* __restrict__ en,
                   const float* __restrict__ men, ushort* __restrict__ attnb,
                   ushort* __restrict__ cols, ushort* __restrict__ vals,
                   int* __restrict__ nnzv, float* __restrict__ linv)
{
    const int i = blockIdx.x;
    const float4* E4 = (const float4*)en;
    const int tid = threadIdx.x, lane = tid & 63, w = tid >> 6;
    const size_t rb = (size_t)i * (NROW / 4);

    // all 12 independent loads upfront
    float4 a4[4], m4[4], ev4[4];
    #pragma unroll
    for (int r = 0; r < 4; ++r) {
        const int t = tid + 256 * r;
        a4[r]  = adj[rb + t];
        m4[r]  = Mm[rb + t];
        ev4[r] = E4[t];
    }
    const float esi  = es[i];
    const float mhat = fmaxf(0.f, esi + men[0]);   // upper bound on e

    ushort mvb[16], po[16];
    unsigned nb = 0;
    float ls = 0.f;
    #pragma unroll
    for (int r = 0; r < 4; ++r) {
        const float av[4]  = {a4[r].x, a4[r].y, a4[r].z, a4[r].w};
        const float mmv[4] = {m4[r].x, m4[r].y, m4[r].z, m4[r].w};
        const float ev[4]  = {ev4[r].x, ev4[r].y, ev4[r].z, ev4[r].w};
        #pragma unroll
        for (int c = 0; c < 4; ++c) {
            const int k = r * 4 + c;
            const ushort o = f2bf(av[c] > 0.f ? mmv[c] : -1.f);
            mvb[k] = o;
            const float mv = bf2f(o);
            float pv = 0.f;
            if (mv >= 0.f) {
                const float tt = (esi + ev[c]) * mv;
                const float ee = (tt >= 0.f) ? tt : ALPHA_SLOPE * tt;
                pv = __expf(ee - mhat);
                nb |= 1u << k;
            }
            const ushort pb = f2bf(pv);
            po[k] = pb;
            ls += bf2f(pb);                 // sum the values the GEMM will see
        }
    }

    // dense write immediately (no reduction dependency)
    ushort4* Ar = (ushort4*)(attnb + (size_t)i * NROW);
    #pragma unroll
    for (int r = 0; r < 4; ++r) {
        ushort4 o;
        o.x = po[r*4+0]; o.y = po[r*4+1]; o.z = po[r*4+2]; o.w = po[r*4+3];
        Ar[tid + 256 * r] = o;
    }

    // combined reductions: sum (ls) + CSR scan (cnt) — one barrier
    const int cnt = __popc(nb);
    int v = cnt;
    #pragma unroll
    for (int off2 = 1; off2 < 64; off2 <<= 1) {
        const int t = __shfl_up(v, off2);
        if (lane >= off2) v += t;
    }
    #pragma unroll
    for (int off = 32; off; off >>= 1) ls += __shfl_xor(ls, off);
    __shared__ float sl[4];
    __shared__ int ws4[4];
    if (lane == 63) ws4[w] = v;
    if (lane == 0)  sl[w] = ls;
    __syncthreads();
    if (tid == 0) {
        linv[i] = 1.0f / (sl[0] + sl[1] + sl[2] + sl[3]);
        const int tot = ws4[0] + ws4[1] + ws4[2] + ws4[3];
        nnzv[i] = (tot > CSRW) ? CSRW : tot;
    }
    int base = v - cnt;
    for (int q = 0; q < w; ++q) base += ws4[q];
    int pos = base;
    #pragma unroll
    for (int r = 0; r < 4; ++r)
        #pragma unroll
        for (int c = 0; c < 4; ++c) {
            const int k = r * 4 + c;
            if ((nb >> k) & 1u) {
                if (pos < CSRW) {
                    cols[(size_t)i * CSRW + pos] = (ushort)(4 * (tid + 256 * r) + c);
                    vals[(size_t)i * CSRW + pos] = mvb[k];
                }
                ++pos;
            }
        }
}

// ===== attn_scatter (v2, layers 2-4): m̂ bound, UNNORMALIZED p + linv =====
__global__ __launch_bounds__(256)
void attn_scatter(const ushort* __restrict__ cols, const ushort* __restrict__ vals,
                  const int* __restrict__ nnzv, const float* __restrict__ es,
                  const float* __restrict__ en, const float* __restrict__ men,
                  ushort* __restrict__ attnb, float* __restrict__ linv)
{
    const int i = blockIdx.x;
    const int tid = threadIdx.x, lane = tid & 63, w = tid >> 6;
    const int nz = nnzv[i];
    const float esi  = es[i];
    const float mhat = fmaxf(0.f, esi + men[0]);

    ushort* Ar = attnb + (size_t)i * NROW;
    float ls = 0.f;
    #pragma unroll
    for (int k = 0; k < 2; ++k) {
        const int j = tid + 256 * k;
        if (j < nz) {
            const int c = cols[(size_t)i * CSRW + j];
            const float mv = bf2f(vals[(size_t)i * CSRW + j]);
            float t = (esi + en[c]) * mv;
            t = (t >= 0.f) ? t : ALPHA_SLOPE * t;
            const ushort pb = f2bf(__expf(t - mhat));
            Ar[c] = pb;
            ls += bf2f(pb);
        }
    }
    #pragma unroll
    for (int off = 32; off; off >>= 1) ls += __shfl_xor(ls, off);
    __shared__ float sl[4];
    if (lane == 0) sl[w] = ls;
    __syncthreads();
    if (tid == 0) linv[i] = 1.0f / (sl[0] + sl[1] + sl[2] + sl[3]);
}

// ================= f32 GEMM (tiny z1 gemm only) =================
__global__ __launch_bounds__(256)
void gemm_f32(const float* __restrict__ A, const float* __restrict__ B,
              float* __restrict__ C, int M, int Nc, int K)
{
    __shared__ float As[16][65];
    __shared__ float Bs[16][65];
    const int tid = threadIdx.x;
    const int tr = tid >> 4;
    const int tc = tid & 15;
    const int row0 = blockIdx.y * 64;
    const int col0 = blockIdx.x * 64;
    float acc[4][4] = {{0.f}};

    for (int k0 = 0; k0 < K; k0 += 16) {
        {
            const int r  = tid >> 2;
            const int c4 = (tid & 3) * 4;
            const float* ap = A + (size_t)(row0 + r) * K + k0 + c4;
            const float4 v = *reinterpret_cast<const float4*>(ap);
            As[c4 + 0][r] = v.x; As[c4 + 1][r] = v.y;
            As[c4 + 2][r] = v.z; As[c4 + 3][r] = v.w;
        }
        {
            const int kk = tid >> 4;
            const int c4 = (tid & 15) * 4;
            const float* bp = B + (size_t)(k0 + kk) * Nc + col0 + c4;
            float4 v;
            if (col0 + c4 + 3 < Nc) {
                v = *reinterpret_cast<const float4*>(bp);
            } else {
                v.x = (col0 + c4 + 0 < Nc) ? bp[0] : 0.f;
                v.y = (col0 + c4 + 1 < Nc) ? bp[1] : 0.f;
                v.z = (col0 + c4 + 2 < Nc) ? bp[2] : 0.f;
                v.w = (col0 + c4 + 3 < Nc) ? bp[3] : 0.f;
            }
            Bs[kk][c4 + 0] = v.x; Bs[kk][c4 + 1] = v.y;
            Bs[kk][c4 + 2] = v.z; Bs[kk][c4 + 3] = v.w;
        }
        __syncthreads();
        #pragma unroll
        for (int k = 0; k < 16; ++k) {
            float a0 = As[k][tr*4+0], a1 = As[k][tr*4+1], a2 = As[k][tr*4+2], a3 = As[k][tr*4+3];
            float b0 = Bs[k][tc*4+0], b1 = Bs[k][tc*4+1], b2 = Bs[k][tc*4+2], b3 = Bs[k][tc*4+3];
            acc[0][0]+=a0*b0; acc[0][1]+=a0*b1; acc[0][2]+=a0*b2; acc[0][3]+=a0*b3;
            acc[1][0]+=a1*b0; acc[1][1]+=a1*b1; acc[1][2]+=a1*b2; acc[1][3]+=a1*b3;
            acc[2][0]+=a2*b0; acc[2][1]+=a2*b1; acc[2][2]+=a2*b2; acc[2][3]+=a2*b3;
            acc[3][0]+=a3*b0; acc[3][1]+=a3*b1; acc[3][2]+=a3*b2; acc[3][3]+=a3*b3;
        }
        __syncthreads();
    }
    #pragma unroll
    for (int i = 0; i < 4; ++i) {
        const int r = row0 + tr * 4 + i;
        #pragma unroll
        for (int j = 0; j < 4; ++j) {
            const int c = col0 + tc * 4 + j;
            if (c < Nc) C[(size_t)r * Nc + c] = acc[i][j];
        }
    }
}

// ================= transpose f32 [R][C] -> bf16 [C][R] (weights prep) =================
__global__ __launch_bounds__(256)
void transpose_bf16(const float* __restrict__ in, ushort* __restrict__ out, int R, int C)
{
    __shared__ float t[32][33];
    const int r0 = blockIdx.y * 32, c0 = blockIdx.x * 32;
    const int j = threadIdx.x & 31;
    for (int i = threadIdx.x >> 5; i < 32; i += 8)
        if (r0 + i < R && c0 + j < C)
            t[i][j] = in[(size_t)(r0 + i) * C + c0 + j];
    __syncthreads();
    for (int i = threadIdx.x >> 5; i < 32; i += 8)
        if (c0 + i < C && r0 + j < R)
            out[(size_t)(c0 + i) * R + r0 + j] = f2bf(t[j][i]);
}

// ===== trans_scores: transpose hW -> bf16 [C][R] + per-band partial row dots =====
__global__ __launch_bounds__(256)
void trans_scores(const float* __restrict__ in, ushort* __restrict__ out,
                  int R, int C, const float* __restrict__ a_self,
                  const float* __restrict__ a_neigh,
                  float* __restrict__ esP, float* __restrict__ enP)
{
    __shared__ float t[32][33];
    const int r0 = blockIdx.y * 32, c0 = blockIdx.x * 32;
    const int j = threadIdx.x & 31;
    for (int i = threadIdx.x >> 5; i < 32; i += 8)
        t[i][j] = (r0 + i < R && c0 + j < C) ? in[(size_t)(r0 + i) * C + c0 + j] : 0.f;
    __syncthreads();
    for (int i = threadIdx.x >> 5; i < 32; i += 8)
        if (c0 + i < C && r0 + j < R)
            out[(size_t)(c0 + i) * R + r0 + j] = f2bf(t[j][i]);

    const int row = threadIdx.x >> 3, k = threadIdx.x & 7;
    float ps = 0.f, pn = 0.f;
    #pragma unroll
    for (int q = 0; q < 4; ++q) {
        const int c = k + q * 8;
        const float hv = t[row][c];
        const float asv = (c0 + c < C) ? a_self[c0 + c] : 0.f;
        const float anv = (c0 + c < C) ? a_neigh[c0 + c] : 0.f;
        ps += hv * asv;
        pn += hv * anv;
    }
    #pragma unroll
    for (int off = 4; off; off >>= 1) {
        ps += __shfl_down(ps, off, 8);
        pn += __shfl_down(pn, off, 8);
    }
    if (k == 0 && r0 + row < R) {
        esP[(size_t)(c0 >> 5) * R + r0 + row] = ps;
        enP[(size_t)(c0 >> 5) * R + r0 + row] = pn;
    }
}

// es[i] = sum_b esP[b][i]; en likewise. Fixed order — deterministic.
__global__ void scores_reduce(const float* __restrict__ esP, const float* __restrict__ enP,
                              float* __restrict__ es, float* __restrict__ en, int nb)
{
    const int i = blockIdx.x * 256 + threadIdx.x;
    if (i < NROW) {
        float s = 0.f, n = 0.f;
        for (int b = 0; b < nb; ++b) {
            s += esP[(size_t)b * NROW + i];
            n += enP[(size_t)b * NROW + i];
        }
        es[i] = s;
        en[i] = n;
    }
}

// ================= f32 -> bf16 convert =================
__global__ void conv_bf16(const float4* __restrict__ in, ushort4* __restrict__ out, int n4)
{
    for (int i = blockIdx.x * 256 + threadIdx.x; i < n4; i += gridDim.x * 256) {
        const float4 v = in[i];
        ushort4 o;
        o.x = f2bf(v.x); o.y = f2bf(v.y); o.z = f2bf(v.z); o.w = f2bf(v.w);
        out[i] = o;
    }
}

// ================= tmat[512][16] = h1^T @ h4 =================
__global__ __launch_bounds__(256)
void ata_kernel(const float* __restrict__ h1, const float* __restrict__ h4,
                float* __restrict__ tmat)
{
    const int r = blockIdx.x;
    float acc[16];
    #pragma unroll
    for (int c = 0; c < 16; ++c) acc[c] = 0.f;
    for (int n = threadIdx.x; n < NROW; n += 256) {
        const float hv = h1[(size_t)n * 512 + r];
        const float* h4r = h4 + (size_t)n * 16;
        #pragma unroll
        for (int c = 0; c < 16; ++c) acc[c] += hv * h4r[c];
    }
    #pragma unroll
    for (int c = 0; c < 16; ++c)
        #pragma unroll
        for (int off = 32; off; off >>= 1) acc[c] += __shfl_down(acc[c], off);
    __shared__ float red[4][16];
    const int lane = threadIdx.x & 63, w = threadIdx.x >> 6;
    if (lane == 0)
        for (int c = 0; c < 16; ++c) red[w][c] = acc[c];
    __syncthreads();
    if (threadIdx.x < 16)
        tmat[r * 16 + threadIdx.x] = red[0][threadIdx.x] + red[1][threadIdx.x] +
                                     red[2][threadIdx.x] + red[3][threadIdx.x];
}

// ================= row L2 normalize =================
__global__ __launch_bounds__(64)
void norm_kernel(const float* __restrict__ z1, float* __restrict__ out)
{
    const int i = blockIdx.x;
    const int lane = threadIdx.x;
    const float v = (lane < 16) ? z1[(size_t)i * 16 + lane] : 0.f;
    float sq = v * v;
    #pragma unroll
    for (int off = 32; off; off >>= 1) sq += __shfl_down(sq, off);
    const float tot = __shfl(sq, 0);
    const float inv = 1.0f / fmaxf(sqrtf(tot), 1e-12f);
    if (lane < 16) out[(size_t)i * 16 + lane] = v * inv;
}

extern "C" void kernel_launch(void* const* d_in, const int* in_sizes, int n_in,
                              void* d_out, int out_size, void* d_ws, size_t ws_size,
                              hipStream_t stream)
{
    const float* x    = (const float*)d_in[0];
    const float* adj  = (const float*)d_in[1];
    const float* Mm   = (const float*)d_in[2];
    const float* enc1 = (const float*)d_in[3];
    const float* enc2 = (const float*)d_in[4];
    const float* emb  = (const float*)d_in[5];
    const float* W1  = (const float*)d_in[6];
    const float* as1 = (const float*)d_in[7];
    const float* an1 = (const float*)d_in[8];
    const float* W2  = (const float*)d_in[9];
    const float* as2 = (const float*)d_in[10];
    const float* an2 = (const float*)d_in[11];
    const float* W3  = (const float*)d_in[12];
    const float* as3 = (const float*)d_in[13];
    const float* an3 = (const float*)d_in[14];
    const float* W4  = (const float*)d_in[15];
    const float* as4 = (const float*)d_in[16];
    const float* an4 = (const float*)d_in[17];
    float* out = (float*)d_out;
    (void)in_sizes; (void)n_in; (void)out_size;

    char* ws = (char*)d_ws;
    size_t off = 0;
    auto alloc = [&](size_t bytes) { char* p = ws + off; off += (bytes + 255) & ~(size_t)255; return p; };

    ushort* attnb = (ushort*)alloc((size_t)NROW * NROW * 2);   // 33.5 MB (also hosts xb)
    ushort* ccols = (ushort*)alloc((size_t)NROW * CSRW * 2);   // 2.6 MB
    ushort* cvals = (ushort*)alloc((size_t)NROW * CSRW * 2);   // 2.6 MB
    int*    cnnz  = (int*)   alloc((size_t)NROW * 4);
    float*  hW    = (float*) alloc((size_t)NROW * 512 * 4);    // 8.4 MB
    ushort* hWT   = (ushort*)alloc((size_t)512 * NROW * 2);    // 4.2 MB
    float*  h1    = (float*) alloc((size_t)NROW * 512 * 4);    // 8.4 MB
    ushort* inb   = (ushort*)alloc((size_t)NROW * 512 * 2);    // 4.2 MB
    float*  h4    = (float*) alloc((size_t)NROW * 16 * 4);
    ushort* W1t   = (ushort*)alloc((size_t)512 * 1024 * 2);
    ushort* W2t   = (ushort*)alloc((size_t)256 * 512 * 2);
    ushort* W3t   = (ushort*)alloc((size_t)64 * 256 * 2);
    ushort* W4t   = (ushort*)alloc((size_t)16 * 64 * 2);
    float*  es    = (float*) alloc(NROW * 4);
    float*  en    = (float*) alloc(NROW * 4);
    float*  men   = (float*) alloc(256);
    float*  linv  = (float*) alloc(NROW * 4);
    float*  esP   = (float*) alloc((size_t)16 * NROW * 4);     // 262 KB
    float*  enP   = (float*) alloc((size_t)16 * NROW * 4);     // 262 KB
    float*  tmat  = (float*) alloc(512 * 16 * 4);
    float*  z1    = (float*) alloc((size_t)NROW * 16 * 4);
    const size_t pbig = (size_t)3 * NROW * 256 * 4 + (size_t)NROW * 512 * 4; // 20.9 MB
    const size_t psml = (size_t)1 * NROW * 512 * 4;            // 8.4 MB
    const bool bigws = ws_size >= off + pbig + (4u << 20);
    float* Pbuf = (float*)alloc(bigws ? pbig : psml);
    ushort* xb = attnb;   // alias: xb dead before attnb first written

    auto grid_for = [&](int n4) { int g = (n4 + 255) / 256; return g > 2048 ? 2048 : g; };

    auto gemm_nr = [&](const ushort* A, const ushort* Bt, float* C,
                       int M, int N, int K, int splits) {
        const int Ks = K / splits;
        if (N >= 128) {
            dim3 grid(N / 128, M / 64, splits);
            gemm_bf16<2, 4><<<grid, 256, 0, stream>>>(A, Bt, C, Pbuf, M, N, K, Ks);
        } else {
            dim3 grid(1, M / 64, splits);
            gemm_bf16<2, 2><<<grid, 256, 0, stream>>>(A, Bt, C, Pbuf, M, N, K, Ks);
        }
    };
    auto gemmb = [&](const ushort* A, const ushort* Bt, float* C,
                     int M, int N, int K, int splits) {
        gemm_nr(A, Bt, C, M, N, K, splits);
        if (splits > 1) {
            const int n4 = M * N / 4;
            reduce_k<<<grid_for(n4), 256, 0, stream>>>((float4*)C, (const float4*)Pbuf,
                                                       splits - 1, n4);
        }
    };
    auto trans = [&](const float* in, ushort* o, int R, int C) {
        dim3 grid((C + 31) / 32, (R + 31) / 32);
        transpose_bf16<<<grid, 256, 0, stream>>>(in, o, R, C);
    };
    auto tscores = [&](const float* in, ushort* o, int C,
                       const float* as, const float* an) {
        dim3 grid((C + 31) / 32, NROW / 32);
        trans_scores<<<grid, 256, 0, stream>>>(in, o, NROW, C, as, an, esP, enP);
        scores_reduce<<<16, 256, 0, stream>>>(esP, enP, es, en, (C + 31) / 32);
        max_en<<<1, 256, 0, stream>>>(en, men);
    };

    const int s_xW1  = 2;
    const int s_att1 = 2;
    const int s_inW2 = bigws ? 4 : 2;
    const int s_att2 = bigws ? 4 : 2;
    const int s_inW3 = 4;
    const int s_att3 = 8;
    const int s_inW4 = 1;
    const int s_att4 = 8;

    // ---- one-time prep
    conv_bf16<<<2048, 256, 0, stream>>>((const float4*)x, (ushort4*)xb, NROW * 1024 / 4);
    trans(W1, W1t, 1024, 512);
    trans(W2, W2t, 512, 256);
    trans(W3, W3t, 256, 64);
    trans(W4, W4t, 64, 16);

    // ---- layer 1: [4096,1024] -> [4096,512]
    gemmb(xb, W1t, hW, NROW, 512, 1024, s_xW1);
    tscores(hW, hWT, 512, as1, an1);
    attn_build_l1<<<NROW, 256, 0, stream>>>((const float4*)adj, (const float4*)Mm,
                                            es, en, men, attnb, ccols, cvals, cnnz, linv);
    gemm_nr(attnb, hWT, hW, NROW, 512, NROW, s_att1);
    finish_layer<<<grid_for(NROW*512/4), 256, 0, stream>>>(
        (const float4*)hW, (const float4*)Pbuf, s_att1 - 1, NROW * 512 / 4,
        (const float4*)enc1, (ushort4*)inb, (float4*)h1, linv, 7);

    // ---- layer 2: [4096,512] -> [4096,256]
    gemmb(inb, W2t, hW, NROW, 256, 512, s_inW2);
    tscores(hW, hWT, 256, as2, an2);
    attn_scatter<<<NROW, 256, 0, stream>>>(ccols, cvals, cnnz, es, en, men, attnb, linv);
    gemm_nr(attnb, hWT, hW, NROW, 256, NROW, s_att2);
    finish_layer<<<grid_for(NROW*256/4), 256, 0, stream>>>(
        (const float4*)hW, (const float4*)Pbuf, s_att2 - 1, NROW * 256 / 4,
        (const float4*)enc2, (ushort4*)inb, (float4*)nullptr, linv, 6);

    // ---- layer 3: [4096,256] -> [4096,64]
    gemmb(inb, W3t, hW, NROW, 64, 256, s_inW3);
    tscores(hW, hWT, 64, as3, an3);
    attn_scatter<<<NROW, 256, 0, stream>>>(ccols, cvals, cnnz, es, en, men, attnb, linv);
    gemm_nr(attnb, hWT, hW, NROW, 64, NROW, s_att3);
    finish_layer<<<grid_for(NROW*64/4), 256, 0, stream>>>(
        (const float4*)hW, (const float4*)Pbuf, s_att3 - 1, NROW * 64 / 4,
        (const float4*)emb, (ushort4*)inb, (float4*)nullptr, linv, 4);

    // ---- layer 4: [4096,64] -> [4096,16]
    gemmb(inb, W4t, hW, NROW, 16, 64, s_inW4);
    tscores(hW, hWT, 16, as4, an4);
    attn_scatter<<<NROW, 256, 0, stream>>>(ccols, cvals, cnnz, es, en, men, attnb, linv);
    gemm_nr(attnb, hWT, hW, NROW, 16, NROW, s_att4);
    finish_layer<<<grid_for(NROW*16/4), 256, 0, stream>>>(
        (const float4*)hW, (const float4*)Pbuf, s_att4 - 1, NROW * 16 / 4,
        (const float4*)nullptr, (ushort4*)nullptr, (float4*)h4, linv, 2);

    // ---- z1 = h1 @ (h1^T @ h4); z = rownorm(z1)
    ata_kernel<<<512, 256, 0, stream>>>(h1, h4, tmat);
    {
        dim3 grid((16 + 63) / 64, NROW / 64);
        gemm_f32<<<grid, 256, 0, stream>>>(h1, tmat, z1, NROW, 16, 512);
    }
    norm_kernel<<<NROW, 64, 0, stream>>>(z1, out);
}

// Round 17
// 285.771 us; speedup vs baseline: 1.0902x; 1.0902x over previous
//
// round 17: identical to round 15/16 (infra retry x2 — UnresponsiveContainer, same stale pod)
// r13 base + width-hybrid PV: dense MFMA GEMM for D=512/256, fused CSR softmax-SpMM for D=64/16
#include <hip/hip_runtime.h>
#include <math.h>

#define NROW 4096
#define ALPHA_SLOPE 0.2f
#define CSRW 320

typedef __attribute__((ext_vector_type(8))) short bf16x8;
typedef __attribute__((ext_vector_type(4))) float f32x4;

__device__ __forceinline__ ushort f2bf(float f) {
    union { float f; unsigned u; } v; v.f = f;
    unsigned r = v.u + 0x7fffu + ((v.u >> 16) & 1u);   // RNE
    return (ushort)(r >> 16);
}
__device__ __forceinline__ float bf2f(ushort u) {
    union { unsigned u; float f; } v; v.u = ((unsigned)u) << 16;
    return v.f;
}

// ================= bf16 MFMA GEMM, BK=64, both-sides-swizzled LDS =================
// Tile (MF*32) x (NF*32), 4 waves (2x2), BK=64, split-K via grid.z.
template<int MF, int NF>
__global__ __launch_bounds__(256)
void gemm_bf16(const ushort* __restrict__ A, const ushort* __restrict__ Bt,
               float* __restrict__ C, float* __restrict__ P,
               int M, int N, int K, int Ks)
{
    constexpr int BM = MF * 32;
    constexpr int BN = NF * 32;
    __shared__ ushort As[BM * 64];
    __shared__ ushort Bs[BN * 64];
    const int tid  = threadIdx.x;
    const int lane = tid & 63;
    const int wave = tid >> 6;
    const int wr = wave >> 1, wc = wave & 1;
    const int row0 = blockIdx.y * BM;
    const int col0 = blockIdx.x * BN;
    const size_t koff = (size_t)blockIdx.z * Ks;

    f32x4 acc[MF][NF];
    #pragma unroll
    for (int i = 0; i < MF; ++i)
        #pragma unroll
        for (int j = 0; j < NF; ++j) acc[i][j] = (f32x4){0.f, 0.f, 0.f, 0.f};

    const ushort* pA[MF]; int dA[MF];
    #pragma unroll
    for (int j = 0; j < MF; ++j) {
        const int s = tid + 256 * j;
        const int r = s >> 3, c = s & 7;
        pA[j] = A + (size_t)(row0 + r) * K + koff + (size_t)(c ^ (r & 7)) * 8;
        dA[j] = s * 8;
    }
    const ushort* pB[NF]; int dB[NF];
    #pragma unroll
    for (int j = 0; j < NF; ++j) {
        const int s = tid + 256 * j;
        const int r = s >> 3, c = s & 7;
        const int rg = (col0 + r < N) ? (col0 + r) : (N - 1);
        pB[j] = Bt + (size_t)rg * K + koff + (size_t)(c ^ (r & 7)) * 8;
        dB[j] = s * 8;
    }

    const int arow0 = wr * (MF * 16) + (lane & 15);
    const int brow0 = wc * (NF * 16) + (lane & 15);
    const int acg   = lane >> 4;

    bf16x8 vA[MF], vB[NF];
    #pragma unroll
    for (int j = 0; j < MF; ++j) vA[j] = *(const bf16x8*)(pA[j]);
    #pragma unroll
    for (int j = 0; j < NF; ++j) vB[j] = *(const bf16x8*)(pB[j]);

    for (int k0 = 0; k0 < Ks; k0 += 64) {
        __syncthreads();
        #pragma unroll
        for (int j = 0; j < MF; ++j) *(bf16x8*)(As + dA[j]) = vA[j];
        #pragma unroll
        for (int j = 0; j < NF; ++j) *(bf16x8*)(Bs + dB[j]) = vB[j];
        __syncthreads();
        if (k0 + 64 < Ks) {
            #pragma unroll
            for (int j = 0; j < MF; ++j) vA[j] = *(const bf16x8*)(pA[j] + k0 + 64);
            #pragma unroll
            for (int j = 0; j < NF; ++j) vB[j] = *(const bf16x8*)(pB[j] + k0 + 64);
        }
        #pragma unroll
        for (int kk = 0; kk < 2; ++kk) {
            const int Q = kk * 4 + acg;
            bf16x8 af[MF], bfr[NF];
            #pragma unroll
            for (int mi = 0; mi < MF; ++mi) {
                const int r = arow0 + mi * 16;
                af[mi] = *(const bf16x8*)(As + (r * 8 + (Q ^ (r & 7))) * 8);
            }
            #pragma unroll
            for (int ni = 0; ni < NF; ++ni) {
                const int r = brow0 + ni * 16;
                bfr[ni] = *(const bf16x8*)(Bs + (r * 8 + (Q ^ (r & 7))) * 8);
            }
            #pragma unroll
            for (int mi = 0; mi < MF; ++mi)
                #pragma unroll
                for (int ni = 0; ni < NF; ++ni)
                    acc[mi][ni] = __builtin_amdgcn_mfma_f32_16x16x32_bf16(
                        af[mi], bfr[ni], acc[mi][ni], 0, 0, 0);
        }
    }

    float* outp = (blockIdx.z == gridDim.z - 1) ? C : (P + (size_t)blockIdx.z * M * N);
    const int crow  = row0 + wr * (MF * 16) + (lane >> 4) * 4;
    const int ccol0 = col0 + wc * (NF * 16) + (lane & 15);
    #pragma unroll
    for (int mi = 0; mi < MF; ++mi)
        #pragma unroll
        for (int ni = 0; ni < NF; ++ni) {
            const int cc = ccol0 + ni * 16;
            if (cc < N) {
                #pragma unroll
                for (int j = 0; j < 4; ++j)
                    outp[(size_t)(crow + mi * 16 + j) * N + cc] = acc[mi][ni][j];
            }
        }
}

// C[i] += sum_{s<nm1} P[s][i]  (fixed order — deterministic)
__global__ void reduce_k(float4* __restrict__ C, const float4* __restrict__ P,
                         int nm1, int n4)
{
    for (int i = blockIdx.x * 256 + threadIdx.x; i < n4; i += gridDim.x * 256) {
        float4 c = C[i];
        for (int s = 0; s < nm1; ++s) {
            const float4 p = P[(size_t)s * n4 + i];
            c.x += p.x; c.y += p.y; c.z += p.z; c.w += p.w;
        }
        C[i] = c;
    }
}

// ===== finish_layer: sum split-K partials, ELU, optional mix -> bf16 / f32 =====
__global__ void finish_layer(const float4* __restrict__ C, const float4* __restrict__ P,
                             int nm1, int n4, const float4* __restrict__ enc,
                             ushort4* __restrict__ outb, float4* __restrict__ outf)
{
    for (int i = blockIdx.x * 256 + threadIdx.x; i < n4; i += gridDim.x * 256) {
        float4 s = C[i];
        for (int t = 0; t < nm1; ++t) {
            const float4 p = P[(size_t)t * n4 + i];
            s.x += p.x; s.y += p.y; s.z += p.z; s.w += p.w;
        }
        float4 h;
        h.x = (s.x > 0.f) ? s.x : expm1f(s.x);
        h.y = (s.y > 0.f) ? s.y : expm1f(s.y);
        h.z = (s.z > 0.f) ? s.z : expm1f(s.z);
        h.w = (s.w > 0.f) ? s.w : expm1f(s.w);
        if (outf) outf[i] = h;
        if (outb) {
            const float4 e = enc[i];
            ushort4 o;
            o.x = f2bf(0.6f * h.x + 0.4f * e.x);
            o.y = f2bf(0.6f * h.y + 0.4f * e.y);
            o.z = f2bf(0.6f * h.z + 0.4f * e.z);
            o.w = f2bf(0.6f * h.w + 0.4f * e.w);
            outb[i] = o;
        }
    }
}

// ===== attn_build_l1 (r13): 12 loads upfront, two-phase softmax, dense attnb + CSR =====
__global__ __launch_bounds__(256)
void attn_build_l1(const float4* __restrict__ adj, const float4* __restrict__ Mm,
                   const float* __restrict__ es, const float* __restrict__ en,
                   ushort* __restrict__ attnb, ushort* __restrict__ cols,
                   ushort* __restrict__ vals, int* __restrict__ nnzv)
{
    const int i = blockIdx.x;
    const float4* E4 = (const float4*)en;
    const int tid = threadIdx.x, lane = tid & 63, w = tid >> 6;
    const size_t rb = (size_t)i * (NROW / 4);

    float4 a4[4], m4[4], ev4[4];
    #pragma unroll
    for (int r = 0; r < 4; ++r) {
        const int t = tid + 256 * r;
        a4[r]  = adj[rb + t];
        m4[r]  = Mm[rb + t];
        ev4[r] = E4[t];
    }
    const float esi = es[i];

    float e[16];
    ushort mvb[16];
    unsigned nb = 0;
    float mx = -3.0e38f;
    #pragma unroll
    for (int r = 0; r < 4; ++r) {
        const float av[4]  = {a4[r].x, a4[r].y, a4[r].z, a4[r].w};
        const float mmv[4] = {m4[r].x, m4[r].y, m4[r].z, m4[r].w};
        const float ev[4]  = {ev4[r].x, ev4[r].y, ev4[r].z, ev4[r].w};
        #pragma unroll
        for (int c = 0; c < 4; ++c) {
            const int k = r * 4 + c;
            const ushort o = f2bf(av[c] > 0.f ? mmv[c] : -1.f);
            mvb[k] = o;
            const float mv = bf2f(o);
            float ee = 0.f;
            if (mv >= 0.f) {
                const float tt = (esi + ev[c]) * mv;
                ee = (tt >= 0.f) ? tt : ALPHA_SLOPE * tt;
                nb |= 1u << k;
                mx = fmaxf(mx, ee);
            }
            e[k] = ee;
        }
    }

    #pragma unroll
    for (int off = 32; off; off >>= 1) mx = fmaxf(mx, __shfl_xor(mx, off));
    __shared__ float sm[4], fin[2];
    __shared__ int ws4[4];
    if (lane == 0) sm[w] = mx;
    __syncthreads();
    const float mf = fmaxf(fmaxf(sm[0], sm[1]), fmaxf(sm[2], sm[3]));
    __syncthreads();

    float ls = 0.f;
    #pragma unroll
    for (int k = 0; k < 16; ++k) {
        if ((nb >> k) & 1u) { e[k] = __expf(e[k] - mf); ls += e[k]; }
        else e[k] = 0.f;
    }
    #pragma unroll
    for (int off = 32; off; off >>= 1) ls += __shfl_xor(ls, off);
    if (lane == 0) sm[w] = ls;
    __syncthreads();
    if (tid == 0) fin[0] = 1.0f / (sm[0] + sm[1] + sm[2] + sm[3]);
    __syncthreads();
    const float inv = fin[0];

    ushort4* Ar = (ushort4*)(attnb + (size_t)i * NROW);
    #pragma unroll
    for (int r = 0; r < 4; ++r) {
        const int t = tid + 256 * r;
        ushort4 o;
        o.x = f2bf(e[r*4+0] * inv);
        o.y = f2bf(e[r*4+1] * inv);
        o.z = f2bf(e[r*4+2] * inv);
        o.w = f2bf(e[r*4+3] * inv);
        Ar[t] = o;
    }

    const int cnt = __popc(nb);
    int v = cnt;
    #pragma unroll
    for (int off2 = 1; off2 < 64; off2 <<= 1) {
        const int t = __shfl_up(v, off2);
        if (lane >= off2) v += t;
    }
    if (lane == 63) ws4[w] = v;
    __syncthreads();
    int base = v - cnt;
    for (int q = 0; q < w; ++q) base += ws4[q];
    int pos = base;
    #pragma unroll
    for (int r = 0; r < 4; ++r)
        #pragma unroll
        for (int c = 0; c < 4; ++c) {
            const int k = r * 4 + c;
            if ((nb >> k) & 1u) {
                if (pos < CSRW) {
                    cols[(size_t)i * CSRW + pos] = (ushort)(4 * (tid + 256 * r) + c);
                    vals[(size_t)i * CSRW + pos] = mvb[k];
                }
                ++pos;
            }
        }
    if (tid == 0) {
        const int tot = ws4[0] + ws4[1] + ws4[2] + ws4[3];
        nnzv[i] = (tot > CSRW) ? CSRW : tot;
    }
}

// ===== attn_scatter (layer 2 only): softmax over CSR, scatter p into attnb =====
__global__ __launch_bounds__(256)
void attn_scatter(const ushort* __restrict__ cols, const ushort* __restrict__ vals,
                  const int* __restrict__ nnzv, const float* __restrict__ es,
                  const float* __restrict__ en, ushort* __restrict__ attnb)
{
    const int i = blockIdx.x;
    const int tid = threadIdx.x, lane = tid & 63, w = tid >> 6;
    const int nz = nnzv[i];
    const float esi = es[i];

    int   cc[2]; float ee[2];
    float m = -3.0e38f;
    #pragma unroll
    for (int k = 0; k < 2; ++k) {
        const int j = tid + 256 * k;
        cc[k] = -1; ee[k] = -3.0e38f;
        if (j < nz) {
            const int c = cols[(size_t)i * CSRW + j];
            const float mv = bf2f(vals[(size_t)i * CSRW + j]);
            float t = (esi + en[c]) * mv;
            t = (t >= 0.f) ? t : ALPHA_SLOPE * t;
            cc[k] = c; ee[k] = t;
            m = fmaxf(m, t);
        }
    }
    #pragma unroll
    for (int off = 32; off; off >>= 1) m = fmaxf(m, __shfl_xor(m, off));
    __shared__ float sm[4];
    if (lane == 0) sm[w] = m;
    __syncthreads();
    const float mf = fmaxf(fmaxf(sm[0], sm[1]), fmaxf(sm[2], sm[3]));
    __syncthreads();

    float l = 0.f;
    #pragma unroll
    for (int k = 0; k < 2; ++k)
        if (cc[k] >= 0) { ee[k] = __expf(ee[k] - mf); l += ee[k]; }
    #pragma unroll
    for (int off = 32; off; off >>= 1) l += __shfl_xor(l, off);
    if (lane == 0) sm[w] = l;
    __syncthreads();
    const float inv = 1.0f / (sm[0] + sm[1] + sm[2] + sm[3]);

    ushort* Ar = attnb + (size_t)i * NROW;
    #pragma unroll
    for (int k = 0; k < 2; ++k)
        if (cc[k] >= 0) Ar[cc[k]] = f2bf(ee[k] * inv);
}

// ===== spmm_attn<D> (layers 3-4): block per row. Softmax over CSR entries (LDS),
// then h'[i,:] = inv * sum_j p~_ij * h[j,:] gathered from bf16 h (L2-resident at
// D<=64). Fused ELU + optional mix. From r10 (refcheck'd there).
template<int D>
__global__ __launch_bounds__(256)
void spmm_attn(const ushort* __restrict__ cols, const ushort* __restrict__ vals,
               const int* __restrict__ nnzv, const float* __restrict__ es,
               const float* __restrict__ en, const ushort* __restrict__ hb,
               const float* __restrict__ enc, ushort* __restrict__ outb,
               float* __restrict__ outf)
{
    constexpr int TPG = D / 2;
    constexpr int G   = 256 / TPG;
    __shared__ ushort lc[CSRW];
    __shared__ float  lp[CSRW];
    __shared__ float  sred[4];
    __shared__ float  r0[256], r1[256];
    const int i = blockIdx.x;
    const int tid = threadIdx.x, lane = tid & 63, w = tid >> 6;
    const int nz = nnzv[i];
    const float esi = es[i];

    float lmax = -3.0e38f;
    for (int j = tid; j < nz; j += 256) {
        const int c = cols[(size_t)i * CSRW + j];
        const float mv = bf2f(vals[(size_t)i * CSRW + j]);
        float e = (esi + en[c]) * mv;
        e = (e >= 0.f) ? e : ALPHA_SLOPE * e;
        lc[j] = (ushort)c;
        lp[j] = e;
        lmax = fmaxf(lmax, e);
    }
    #pragma unroll
    for (int off = 32; off; off >>= 1) lmax = fmaxf(lmax, __shfl_xor(lmax, off));
    if (lane == 0) sred[w] = lmax;
    __syncthreads();
    const float m = fmaxf(fmaxf(sred[0], sred[1]), fmaxf(sred[2], sred[3]));
    __syncthreads();

    float ls = 0.f;
    for (int j = tid; j < nz; j += 256) {
        const float p = __expf(lp[j] - m);
        lp[j] = p;
        ls += p;
    }
    #pragma unroll
    for (int off = 32; off; off >>= 1) ls += __shfl_xor(ls, off);
    if (lane == 0) sred[w] = ls;
    __syncthreads();
    const float inv = 1.0f / (sred[0] + sred[1] + sred[2] + sred[3]);

    const int g = tid / TPG, c2 = (tid % TPG) * 2;
    float a0 = 0.f, a1 = 0.f;
    for (int j = g; j < nz; j += G) {
        const float p = lp[j];
        const unsigned u = *(const unsigned*)(hb + (size_t)lc[j] * D + c2);
        union { unsigned u; float f; } f0, f1;
        f0.u = u << 16;
        f1.u = u & 0xffff0000u;
        a0 += p * f0.f;
        a1 += p * f1.f;
    }
    if (G > 1) {
        r0[tid] = a0; r1[tid] = a1;
        __syncthreads();
        if (g == 0) {
            #pragma unroll
            for (int q = 1; q < G; ++q) {
                a0 += r0[q * TPG + tid];
                a1 += r1[q * TPG + tid];
            }
        }
    }
    if (g == 0) {
        a0 *= inv; a1 *= inv;
        const float h0 = (a0 > 0.f) ? a0 : expm1f(a0);
        const float h1 = (a1 > 0.f) ? a1 : expm1f(a1);
        const size_t o = (size_t)i * D + c2;
        if (outf) { outf[o] = h0; outf[o + 1] = h1; }
        if (outb) {
            const float e0 = enc[o], e1 = enc[o + 1];
            const unsigned pk = ((unsigned)f2bf(0.6f * h1 + 0.4f * e1) << 16)
                              | (unsigned)f2bf(0.6f * h0 + 0.4f * e0);
            *(unsigned*)(outb + o) = pk;
        }
    }
}

// ================= f32 GEMM (tiny z1 gemm only) =================
__global__ __launch_bounds__(256)
void gemm_f32(const float* __restrict__ A, const float* __restrict__ B,
              float* __restrict__ C, int M, int Nc, int K)
{
    __shared__ float As[16][65];
    __shared__ float Bs[16][65];
    const int tid = threadIdx.x;
    const int tr = tid >> 4;
    const int tc = tid & 15;
    const int row0 = blockIdx.y * 64;
    const int col0 = blockIdx.x * 64;
    float acc[4][4] = {{0.f}};

    for (int k0 = 0; k0 < K; k0 += 16) {
        {
            const int r  = tid >> 2;
            const int c4 = (tid & 3) * 4;
            const float* ap = A + (size_t)(row0 + r) * K + k0 + c4;
            const float4 v = *reinterpret_cast<const float4*>(ap);
            As[c4 + 0][r] = v.x; As[c4 + 1][r] = v.y;
            As[c4 + 2][r] = v.z; As[c4 + 3][r] = v.w;
        }
        {
            const int kk = tid >> 4;
            const int c4 = (tid & 15) * 4;
            const float* bp = B + (size_t)(k0 + kk) * Nc + col0 + c4;
            float4 v;
            if (col0 + c4 + 3 < Nc) {
                v = *reinterpret_cast<const float4*>(bp);
            } else {
                v.x = (col0 + c4 + 0 < Nc) ? bp[0] : 0.f;
                v.y = (col0 + c4 + 1 < Nc) ? bp[1] : 0.f;
                v.z = (col0 + c4 + 2 < Nc) ? bp[2] : 0.f;
                v.w = (col0 + c4 + 3 < Nc) ? bp[3] : 0.f;
            }
            Bs[kk][c4 + 0] = v.x; Bs[kk][c4 + 1] = v.y;
            Bs[kk][c4 + 2] = v.z; Bs[kk][c4 + 3] = v.w;
        }
        __syncthreads();
        #pragma unroll
        for (int k = 0; k < 16; ++k) {
            float a0 = As[k][tr*4+0], a1 = As[k][tr*4+1], a2 = As[k][tr*4+2], a3 = As[k][tr*4+3];
            float b0 = Bs[k][tc*4+0], b1 = Bs[k][tc*4+1], b2 = Bs[k][tc*4+2], b3 = Bs[k][tc*4+3];
            acc[0][0]+=a0*b0; acc[0][1]+=a0*b1; acc[0][2]+=a0*b2; acc[0][3]+=a0*b3;
            acc[1][0]+=a1*b0; acc[1][1]+=a1*b1; acc[1][2]+=a1*b2; acc[1][3]+=a1*b3;
            acc[2][0]+=a2*b0; acc[2][1]+=a2*b1; acc[2][2]+=a2*b2; acc[2][3]+=a2*b3;
            acc[3][0]+=a3*b0; acc[3][1]+=a3*b1; acc[3][2]+=a3*b2; acc[3][3]+=a3*b3;
        }
        __syncthreads();
    }
    #pragma unroll
    for (int i = 0; i < 4; ++i) {
        const int r = row0 + tr * 4 + i;
        #pragma unroll
        for (int j = 0; j < 4; ++j) {
            const int c = col0 + tc * 4 + j;
            if (c < Nc) C[(size_t)r * Nc + c] = acc[i][j];
        }
    }
}

// ================= transpose f32 [R][C] -> bf16 [C][R] (weights prep) =================
__global__ __launch_bounds__(256)
void transpose_bf16(const float* __restrict__ in, ushort* __restrict__ out, int R, int C)
{
    __shared__ float t[32][33];
    const int r0 = blockIdx.y * 32, c0 = blockIdx.x * 32;
    const int j = threadIdx.x & 31;
    for (int i = threadIdx.x >> 5; i < 32; i += 8)
        if (r0 + i < R && c0 + j < C)
            t[i][j] = in[(size_t)(r0 + i) * C + c0 + j];
    __syncthreads();
    for (int i = threadIdx.x >> 5; i < 32; i += 8)
        if (c0 + i < C && r0 + j < R)
            out[(size_t)(c0 + i) * R + r0 + j] = f2bf(t[j][i]);
}

// ===== trans_scores: transpose hW -> bf16 [C][R] + per-band partial row dots =====
__global__ __launch_bounds__(256)
void trans_scores(const float* __restrict__ in, ushort* __restrict__ out,
                  int R, int C, const float* __restrict__ a_self,
                  const float* __restrict__ a_neigh,
                  float* __restrict__ esP, float* __restrict__ enP)
{
    __shared__ float t[32][33];
    const int r0 = blockIdx.y * 32, c0 = blockIdx.x * 32;
    const int j = threadIdx.x & 31;
    for (int i = threadIdx.x >> 5; i < 32; i += 8)
        t[i][j] = (r0 + i < R && c0 + j < C) ? in[(size_t)(r0 + i) * C + c0 + j] : 0.f;
    __syncthreads();
    for (int i = threadIdx.x >> 5; i < 32; i += 8)
        if (c0 + i < C && r0 + j < R)
            out[(size_t)(c0 + i) * R + r0 + j] = f2bf(t[j][i]);

    const int row = threadIdx.x >> 3, k = threadIdx.x & 7;
    float ps = 0.f, pn = 0.f;
    #pragma unroll
    for (int q = 0; q < 4; ++q) {
        const int c = k + q * 8;
        const float hv = t[row][c];
        const float asv = (c0 + c < C) ? a_self[c0 + c] : 0.f;
        const float anv = (c0 + c < C) ? a_neigh[c0 + c] : 0.f;
        ps += hv * asv;
        pn += hv * anv;
    }
    #pragma unroll
    for (int off = 4; off; off >>= 1) {
        ps += __shfl_down(ps, off, 8);
        pn += __shfl_down(pn, off, 8);
    }
    if (k == 0 && r0 + row < R) {
        esP[(size_t)(c0 >> 5) * R + r0 + row] = ps;
        enP[(size_t)(c0 >> 5) * R + r0 + row] = pn;
    }
}

// es[i] = sum_b esP[b][i]; en likewise. Fixed order — deterministic.
__global__ void scores_reduce(const float* __restrict__ esP, const float* __restrict__ enP,
                              float* __restrict__ es, float* __restrict__ en, int nb)
{
    const int i = blockIdx.x * 256 + threadIdx.x;
    if (i < NROW) {
        float s = 0.f, n = 0.f;
        for (int b = 0; b < nb; ++b) {
            s += esP[(size_t)b * NROW + i];
            n += enP[(size_t)b * NROW + i];
        }
        es[i] = s;
        en[i] = n;
    }
}

// ================= f32 -> bf16 convert =================
__global__ void conv_bf16(const float4* __restrict__ in, ushort4* __restrict__ out, int n4)
{
    for (int i = blockIdx.x * 256 + threadIdx.x; i < n4; i += gridDim.x * 256) {
        const float4 v = in[i];
        ushort4 o;
        o.x = f2bf(v.x); o.y = f2bf(v.y); o.z = f2bf(v.z); o.w = f2bf(v.w);
        out[i] = o;
    }
}

// ================= tmat[512][16] = h1^T @ h4 =================
__global__ __launch_bounds__(256)
void ata_kernel(const float* __restrict__ h1, const float* __restrict__ h4,
                float* __restrict__ tmat)
{
    const int r = blockIdx.x;
    float acc[16];
    #pragma unroll
    for (int c = 0; c < 16; ++c) acc[c] = 0.f;
    for (int n = threadIdx.x; n < NROW; n += 256) {
        const float hv = h1[(size_t)n * 512 + r];
        const float* h4r = h4 + (size_t)n * 16;
        #pragma unroll
        for (int c = 0; c < 16; ++c) acc[c] += hv * h4r[c];
    }
    #pragma unroll
    for (int c = 0; c < 16; ++c)
        #pragma unroll
        for (int off = 32; off; off >>= 1) acc[c] += __shfl_down(acc[c], off);
    __shared__ float red[4][16];
    const int lane = threadIdx.x & 63, w = threadIdx.x >> 6;
    if (lane == 0)
        for (int c = 0; c < 16; ++c) red[w][c] = acc[c];
    __syncthreads();
    if (threadIdx.x < 16)
        tmat[r * 16 + threadIdx.x] = red[0][threadIdx.x] + red[1][threadIdx.x] +
                                     red[2][threadIdx.x] + red[3][threadIdx.x];
}

// ================= row L2 normalize =================
__global__ __launch_bounds__(64)
void norm_kernel(const float* __restrict__ z1, float* __restrict__ out)
{
    const int i = blockIdx.x;
    const int lane = threadIdx.x;
    const float v = (lane < 16) ? z1[(size_t)i * 16 + lane] : 0.f;
    float sq = v * v;
    #pragma unroll
    for (int off = 32; off; off >>= 1) sq += __shfl_down(sq, off);
    const float tot = __shfl(sq, 0);
    const float inv = 1.0f / fmaxf(sqrtf(tot), 1e-12f);
    if (lane < 16) out[(size_t)i * 16 + lane] = v * inv;
}

extern "C" void kernel_launch(void* const* d_in, const int* in_sizes, int n_in,
                              void* d_out, int out_size, void* d_ws, size_t ws_size,
                              hipStream_t stream)
{
    const float* x    = (const float*)d_in[0];
    const float* adj  = (const float*)d_in[1];
    const float* Mm   = (const float*)d_in[2];
    const float* enc1 = (const float*)d_in[3];
    const float* enc2 = (const float*)d_in[4];
    const float* emb  = (const float*)d_in[5];
    const float* W1  = (const float*)d_in[6];
    const float* as1 = (const float*)d_in[7];
    const float* an1 = (const float*)d_in[8];
    const float* W2  = (const float*)d_in[9];
    const float* as2 = (const float*)d_in[10];
    const float* an2 = (const float*)d_in[11];
    const float* W3  = (const float*)d_in[12];
    const float* as3 = (const float*)d_in[13];
    const float* an3 = (const float*)d_in[14];
    const float* W4  = (const float*)d_in[15];
    const float* as4 = (const float*)d_in[16];
    const float* an4 = (const float*)d_in[17];
    float* out = (float*)d_out;
    (void)in_sizes; (void)n_in; (void)out_size;

    char* ws = (char*)d_ws;
    size_t off = 0;
    auto alloc = [&](size_t bytes) { char* p = ws + off; off += (bytes + 255) & ~(size_t)255; return p; };

    ushort* attnb = (ushort*)alloc((size_t)NROW * NROW * 2);   // 33.5 MB (also hosts xb)
    ushort* ccols = (ushort*)alloc((size_t)NROW * CSRW * 2);   // 2.6 MB
    ushort* cvals = (ushort*)alloc((size_t)NROW * CSRW * 2);   // 2.6 MB
    int*    cnnz  = (int*)   alloc((size_t)NROW * 4);
    float*  hW    = (float*) alloc((size_t)NROW * 512 * 4);    // 8.4 MB
    ushort* hWT   = (ushort*)alloc((size_t)512 * NROW * 2);    // 4.2 MB
    ushort* hWb   = (ushort*)alloc((size_t)NROW * 64 * 2);     // 0.5 MB (row-major, D<=64)
    float*  h1    = (float*) alloc((size_t)NROW * 512 * 4);    // 8.4 MB
    ushort* inb   = (ushort*)alloc((size_t)NROW * 512 * 2);    // 4.2 MB
    float*  h4    = (float*) alloc((size_t)NROW * 16 * 4);
    ushort* W1t   = (ushort*)alloc((size_t)512 * 1024 * 2);
    ushort* W2t   = (ushort*)alloc((size_t)256 * 512 * 2);
    ushort* W3t   = (ushort*)alloc((size_t)64 * 256 * 2);
    ushort* W4t   = (ushort*)alloc((size_t)16 * 64 * 2);
    float*  es    = (float*) alloc(NROW * 4);
    float*  en    = (float*) alloc(NROW * 4);
    float*  esP   = (float*) alloc((size_t)16 * NROW * 4);     // 262 KB
    float*  enP   = (float*) alloc((size_t)16 * NROW * 4);     // 262 KB
    float*  tmat  = (float*) alloc(512 * 16 * 4);
    float*  z1    = (float*) alloc((size_t)NROW * 16 * 4);
    const size_t pbig = (size_t)3 * NROW * 256 * 4 + (size_t)NROW * 512 * 4; // 20.9 MB
    const size_t psml = (size_t)1 * NROW * 512 * 4;            // 8.4 MB
    const bool bigws = ws_size >= off + pbig + (4u << 20);
    float* Pbuf = (float*)alloc(bigws ? pbig : psml);
    ushort* xb = attnb;   // alias: xb dead before attnb first written

    auto grid_for = [&](int n4) { int g = (n4 + 255) / 256; return g > 2048 ? 2048 : g; };

    auto gemm_nr = [&](const ushort* A, const ushort* Bt, float* C,
                       int M, int N, int K, int splits) {
        const int Ks = K / splits;
        if (N >= 128) {
            dim3 grid(N / 128, M / 64, splits);
            gemm_bf16<2, 4><<<grid, 256, 0, stream>>>(A, Bt, C, Pbuf, M, N, K, Ks);
        } else {
            dim3 grid(1, M / 64, splits);
            gemm_bf16<2, 2><<<grid, 256, 0, stream>>>(A, Bt, C, Pbuf, M, N, K, Ks);
        }
    };
    auto gemmb = [&](const ushort* A, const ushort* Bt, float* C,
                     int M, int N, int K, int splits) {
        gemm_nr(A, Bt, C, M, N, K, splits);
        if (splits > 1) {
            const int n4 = M * N / 4;
            reduce_k<<<grid_for(n4), 256, 0, stream>>>((float4*)C, (const float4*)Pbuf,
                                                       splits - 1, n4);
        }
    };
    auto trans = [&](const float* in, ushort* o, int R, int C) {
        dim3 grid((C + 31) / 32, (R + 31) / 32);
        transpose_bf16<<<grid, 256, 0, stream>>>(in, o, R, C);
    };
    auto tscores = [&](const float* in, ushort* o, int C,
                       const float* as, const float* an) {
        dim3 grid((C + 31) / 32, NROW / 32);
        trans_scores<<<grid, 256, 0, stream>>>(in, o, NROW, C, as, an, esP, enP);
        scores_reduce<<<16, 256, 0, stream>>>(esP, enP, es, en, (C + 31) / 32);
    };

    const int s_xW1  = 2;
    const int s_att1 = 2;
    const int s_inW2 = bigws ? 4 : 2;
    const int s_att2 = bigws ? 4 : 2;
    const int s_inW3 = 4;
    const int s_inW4 = 1;

    // ---- one-time prep
    conv_bf16<<<2048, 256, 0, stream>>>((const float4*)x, (ushort4*)xb, NROW * 1024 / 4);
    trans(W1, W1t, 1024, 512);
    trans(W2, W2t, 512, 256);
    trans(W3, W3t, 256, 64);
    trans(W4, W4t, 64, 16);

    // ---- layer 1: [4096,1024] -> [4096,512]  (dense PV)
    gemmb(xb, W1t, hW, NROW, 512, 1024, s_xW1);
    tscores(hW, hWT, 512, as1, an1);
    attn_build_l1<<<NROW, 256, 0, stream>>>((const float4*)adj, (const float4*)Mm,
                                            es, en, attnb, ccols, cvals, cnnz);
    gemm_nr(attnb, hWT, hW, NROW, 512, NROW, s_att1);
    finish_layer<<<grid_for(NROW*512/4), 256, 0, stream>>>(
        (const float4*)hW, (const float4*)Pbuf, s_att1 - 1, NROW * 512 / 4,
        (const float4*)enc1, (ushort4*)inb, (float4*)h1);

    // ---- layer 2: [4096,512] -> [4096,256]  (dense PV)
    gemmb(inb, W2t, hW, NROW, 256, 512, s_inW2);
    tscores(hW, hWT, 256, as2, an2);
    attn_scatter<<<NROW, 256, 0, stream>>>(ccols, cvals, cnnz, es, en, attnb);
    gemm_nr(attnb, hWT, hW, NROW, 256, NROW, s_att2);
    finish_layer<<<grid_for(NROW*256/4), 256, 0, stream>>>(
        (const float4*)hW, (const float4*)Pbuf, s_att2 - 1, NROW * 256 / 4,
        (const float4*)enc2, (ushort4*)inb, (float4*)nullptr);

    // ---- layer 3: [4096,256] -> [4096,64]  (SpMM PV — h table 512KB, L2-resident)
    gemmb(inb, W3t, hW, NROW, 64, 256, s_inW3);
    tscores(hW, hWT, 64, as3, an3);                       // es/en (hWT unused here)
    conv_bf16<<<grid_for(NROW*64/4), 256, 0, stream>>>((const float4*)hW,
                                                       (ushort4*)hWb, NROW * 64 / 4);
    spmm_attn<64><<<NROW, 256, 0, stream>>>(ccols, cvals, cnnz, es, en, hWb,
                                            emb, inb, (float*)nullptr);

    // ---- layer 4: [4096,64] -> [4096,16]  (SpMM PV — h table 128KB)
    gemmb(inb, W4t, hW, NROW, 16, 64, s_inW4);
    tscores(hW, hWT, 16, as4, an4);
    conv_bf16<<<grid_for(NROW*16/4), 256, 0, stream>>>((const float4*)hW,
                                                       (ushort4*)hWb, NROW * 16 / 4);
    spmm_attn<16><<<NROW, 256, 0, stream>>>(ccols, cvals, cnnz, es, en, hWb,
                                            (const float*)nullptr, (ushort*)nullptr, h4);

    // ---- z1 = h1 @ (h1^T @ h4); z = rownorm(z1)
    ata_kernel<<<512, 256, 0, stream>>>(h1, h4, tmat);
    {
        dim3 grid((16 + 63) / 64, NROW / 64);
        gemm_f32<<<grid, 256, 0, stream>>>(h1, tmat, z1, NROW, 16, 512);
    }
    norm_kernel<<<NROW, 64, 0, stream>>>(z1, out);
}